// Round 11
// baseline (111.610 us; speedup 1.0000x reference)
//
#include <hip/hip_runtime.h>

// QuantumDMRGLayer: B=2048, L=196, M=16, NBL=10, pos_label=98 (fixed by setup).
// Round-11: halve the serial chain via SITE-PAIRING. For consecutive sites,
//   W_p W_{p+1} = sum_ab x_a x'_b (A_a A_b)  -- the 4 products A_a A_b are
// sample-SHARED, so prep precomputes them (fp32). Chain does one update per
// pair: two independent MFMA split-bf16 triples (G1=[P00|P01], G2=[P10|P11])
// + 4-coefficient combine + ONE pack per 2 sites. Serial iterations: 49 (L),
// 48 (R) instead of 98/96; critical path per site ~halved; VALU/site -30%.
// Verified machinery kept from r7-r10: pi = bit2<->bit3 row permutation baked
// into G so each lane's D regs are its own B k-half (zero cross-lane ops);
// 2-slot register prefetch ring; split-bf16 Da=Gh*Vh || Db=Gh*Vl+Gl*Vh
// (drops only the ~2^-18 Gl*Vl term); separate r9 out_kernel via WST.
//   left  pair q (sites 2q,2q+1):    P_ab = A_a[2q]A_b[2q+1],
//         c_ab = x[col 2q+1][a]*x[col 2q+2][b]   (row-vector chain)
//   right pair q (sites 193-2q,192-2q): P_ab = A_a[192-2q]A_b[193-2q],
//         c_ab = x[col 193-2q][a]*x[col 194-2q][b] (column-vector chain)
// G layout per pair: G1h|G1l|G2h|G2l, 256 dw each; G_a[(d,nn),k]:
//   left  = P_{a,d}[k,nn]   right = P_{a,d}[nn,k]
// D1[j]<->c00(P00), D1[j+8]<->c01(P01), D2[j]<->c10, D2[j+8]<->c11.

typedef __attribute__((ext_vector_type(8))) short short8;
typedef __attribute__((ext_vector_type(16))) float floatx16;
typedef __attribute__((ext_vector_type(2))) float float2v;

#define PAIR_DW 1024                 // dwords per pair (4 matrices x 256)
#define GDIR_DW (50 * PAIR_DW)       // 50 pairs per dir (incl. pads)
#define STATE_DW (2 * GDIR_DW)       // float offset of state in d_ws
// state: [dir][2048][16] floats

__device__ __forceinline__ unsigned bf16_rne(unsigned u) {
    return (u + 0x7FFFu + ((u >> 16) & 1u)) >> 16;
}

// ---- prep: per (dir,pair) block, build 4 product matrices, split, store ----
__global__ __launch_bounds__(256)
void prep_kernel(const float* __restrict__ AM, unsigned* __restrict__ WS)
{
    const int bid = blockIdx.x;                // 0..99
    const int dir = bid / 50;
    const int q   = bid % 50;
    const int t   = threadIdx.x;

    __shared__ float sF[512];                  // first-applied site [d][i][j]
    __shared__ float sS[512];                  // second-applied site

    int i0, i1; bool valid;
    if (dir == 0) { i0 = 2 * q;       i1 = 2 * q + 1;   valid = (q < 49); }
    else          { i0 = 193 - 2 * q; i1 = 192 - 2 * q; valid = (q < 48); }
    if (valid) {
        ((float2*)sF)[t] = ((const float2*)(AM + i0 * 512))[t];
        ((float2*)sS)[t] = ((const float2*)(AM + i1 * 512))[t];
    } else {
        ((float2*)sF)[t] = make_float2(0.f, 0.f);
        ((float2*)sS)[t] = make_float2(0.f, 0.f);
    }
    __syncthreads();

    const int w    = t & 3;
    const int lane = t >> 2;
    const int kb = (lane >> 5) << 3;
    const int r  = lane & 31;
    const int rr = (r & 0x13) | ((r & 4) << 1) | ((r & 8) >> 1);  // pi(r)
    const int d = rr >> 4, nn = rr & 15;
    const int k0 = kb + 2 * w;

    // G1 (a=0) and G2 (a=1), two k values each
    float g10 = 0.f, g11 = 0.f, g20 = 0.f, g21 = 0.f;
    if (dir == 0) {
        // left: G_a[(d,nn),k] = P_{a,d}[k,nn] = sum_u sF[a][k][u]*sS[d][u][nn]
#pragma unroll
        for (int u = 0; u < 16; ++u) {
            const float s2 = sS[d * 256 + u * 16 + nn];
            g10 = fmaf(sF[      k0 * 16 + u],       s2, g10);
            g11 = fmaf(sF[      (k0 + 1) * 16 + u], s2, g11);
            g20 = fmaf(sF[256 + k0 * 16 + u],       s2, g20);
            g21 = fmaf(sF[256 + (k0 + 1) * 16 + u], s2, g21);
        }
    } else {
        // right: G_a[(d,nn),k] = P_{a,d}[nn,k] = sum_u sS[a][nn][u]*sF[d][u][k]
#pragma unroll
        for (int u = 0; u < 16; ++u) {
            const float f0 = sF[d * 256 + u * 16 + k0];
            const float f1 = sF[d * 256 + u * 16 + k0 + 1];
            const float a0 = sS[      nn * 16 + u];
            const float a1 = sS[256 + nn * 16 + u];
            g10 = fmaf(a0, f0, g10);  g11 = fmaf(a0, f1, g11);
            g20 = fmaf(a1, f0, g20);  g21 = fmaf(a1, f1, g21);
        }
    }

    unsigned* gp = WS + (dir * 50 + q) * PAIR_DW;
    // split-bf16 and store (dword = two consecutive k, low half = k0)
    {
        const unsigned h0 = bf16_rne(__float_as_uint(g10));
        const unsigned h1 = bf16_rne(__float_as_uint(g11));
        const unsigned l0 = bf16_rne(__float_as_uint(
            g10 - __uint_as_float(h0 << 16)));
        const unsigned l1 = bf16_rne(__float_as_uint(
            g11 - __uint_as_float(h1 << 16)));
        gp[t]       = (h1 << 16) | h0;
        gp[256 + t] = (l1 << 16) | l0;
    }
    {
        const unsigned h0 = bf16_rne(__float_as_uint(g20));
        const unsigned h1 = bf16_rne(__float_as_uint(g21));
        const unsigned l0 = bf16_rne(__float_as_uint(
            g20 - __uint_as_float(h0 << 16)));
        const unsigned l1 = bf16_rne(__float_as_uint(
            g21 - __uint_as_float(h1 << 16)));
        gp[512 + t] = (h1 << 16) | h0;
        gp[768 + t] = (l1 << 16) | l0;
    }
}

// ---- main chain: 1 wave = 32 samples x 1 direction, pair steps ----
__global__ __launch_bounds__(64, 1)
void chain_kernel(const float* __restrict__ X,
                  const float* __restrict__ AL,
                  const float* __restrict__ AR,
                  const unsigned* __restrict__ WS,
                  float* __restrict__ WST)
{
    const int lane = threadIdx.x;              // 0..63
    const int dir  = blockIdx.x & 1;
    const int s    = (blockIdx.x >> 1) * 32 + (lane & 31);
    const int kb   = (lane >> 5) << 3;         // this lane's k-half base
    const float* Xs = X + s * 392;
    const unsigned* Gb = WS + dir * GDIR_DW + lane * 4;

    float2v w2[4];
    int4 vh4, vl4;
    auto packv = [&]() {                       // fp32 -> packed bf16 hi/lo
#pragma unroll
        for (int q = 0; q < 4; ++q) {
            const unsigned u0 = __float_as_uint(w2[q].x);
            const unsigned u1 = __float_as_uint(w2[q].y);
            float2v hi;
            hi.x = __uint_as_float(u0 & 0xFFFF0000u);
            hi.y = __uint_as_float(u1 & 0xFFFF0000u);
            const float2v lo = w2[q] - hi;
            ((unsigned*)&vh4)[q] = __builtin_amdgcn_perm(u1, u0, 0x07060302u);
            ((unsigned*)&vl4)[q] = __builtin_amdgcn_perm(
                __float_as_uint(lo.y), __float_as_uint(lo.x), 0x07060302u);
        }
    };

    // ---- init bond vector ----
    const float* Ai = dir ? AR : AL;
    const float2 xi = *(const float2*)(Xs + (dir ? 390 : 0));
#pragma unroll
    for (int q = 0; q < 4; ++q) {
        w2[q].x = xi.x * Ai[kb + 2 * q]     + xi.y * Ai[16 + kb + 2 * q];
        w2[q].y = xi.x * Ai[kb + 2 * q + 1] + xi.y * Ai[16 + kb + 2 * q + 1];
    }
    packv();

    // x-pair offsets: left pair p: xa = col 2p+1 (off 4p+2), xb = col 2p+2
    // (off 4p+4); right pair p: xa = col 193-2p (off 386-4p), xb = 388-4p.
    auto xoffA = [&](int p) { return dir ? (386 - 4 * p) : (4 * p + 2); };
    auto xoffB = [&](int p) { return dir ? (388 - 4 * p) : (4 * p + 4); };

    // ---- 2-slot register prefetch ring ----
    int4 G1H[2], G1L[2], G2H[2], G2L[2];
    float2 xa[2], xb[2];
#pragma unroll
    for (int i = 0; i < 2; ++i) {
        const unsigned* gp = Gb + i * PAIR_DW;
        G1H[i] = *(const int4*)(gp);
        G1L[i] = *(const int4*)(gp + 256);
        G2H[i] = *(const int4*)(gp + 512);
        G2L[i] = *(const int4*)(gp + 768);
        xa[i] = *(const float2*)(Xs + xoffA(i));
        xb[i] = *(const float2*)(Xs + xoffB(i));
    }

    auto pair_step = [&](int sl, bool pf, int pn) {
        const short8 a1h = *(short8*)&G1H[sl];
        const short8 a1l = *(short8*)&G1L[sl];
        const short8 a2h = *(short8*)&G2H[sl];
        const short8 a2l = *(short8*)&G2L[sl];
        const short8 bh = *(short8*)&vh4;
        const short8 bl = *(short8*)&vl4;
        floatx16 Da1 = {}, Db1 = {}, Da2 = {}, Db2 = {};
        Da1 = __builtin_amdgcn_mfma_f32_32x32x16_bf16(a1h, bh, Da1, 0, 0, 0);
        Da2 = __builtin_amdgcn_mfma_f32_32x32x16_bf16(a2h, bh, Da2, 0, 0, 0);
        Db1 = __builtin_amdgcn_mfma_f32_32x32x16_bf16(a1h, bl, Db1, 0, 0, 0);
        Db2 = __builtin_amdgcn_mfma_f32_32x32x16_bf16(a2h, bl, Db2, 0, 0, 0);
        Db1 = __builtin_amdgcn_mfma_f32_32x32x16_bf16(a1l, bh, Db1, 0, 0, 0);
        Db2 = __builtin_amdgcn_mfma_f32_32x32x16_bf16(a2l, bh, Db2, 0, 0, 0);
        const float2 va = xa[sl], vb = xb[sl];
        if (pf) {
            const unsigned* gp = Gb + pn * PAIR_DW;
            G1H[sl] = *(const int4*)(gp);
            G1L[sl] = *(const int4*)(gp + 256);
            G2H[sl] = *(const int4*)(gp + 512);
            G2L[sl] = *(const int4*)(gp + 768);
            xa[sl] = *(const float2*)(Xs + xoffA(pn));
            xb[sl] = *(const float2*)(Xs + xoffB(pn));
        }
        const float2v C00 = {va.x * vb.x, va.x * vb.x};
        const float2v C01 = {va.x * vb.y, va.x * vb.y};
        const float2v C10 = {va.y * vb.x, va.y * vb.x};
        const float2v C11 = {va.y * vb.y, va.y * vb.y};
#pragma unroll
        for (int q = 0; q < 4; ++q) {
            const float2v s1l = float2v{Da1[2*q],   Da1[2*q+1]} +
                                float2v{Db1[2*q],   Db1[2*q+1]};
            const float2v s1h = float2v{Da1[2*q+8], Da1[2*q+9]} +
                                float2v{Db1[2*q+8], Db1[2*q+9]};
            const float2v s2l = float2v{Da2[2*q],   Da2[2*q+1]} +
                                float2v{Db2[2*q],   Db2[2*q+1]};
            const float2v s2h = float2v{Da2[2*q+8], Da2[2*q+9]} +
                                float2v{Db2[2*q+8], Db2[2*q+9]};
            w2[q] = __builtin_elementwise_fma(C00, s1l,
                    __builtin_elementwise_fma(C01, s1h,
                    __builtin_elementwise_fma(C10, s2l, C11 * s2h)));
        }
        packv();
    };

    // ---- 48 common pairs; left has one extra (pair 48 = sites 96,97) ----
    for (int p = 0; p < 48; ++p)
        pair_step(p & 1, true, p + 2);         // pn <= 49, pads exist
    if (dir == 0)
        pair_step(0, false, 0);                // pair 48 sits in slot 0

    // ---- final state (fp32): comps kb..kb+7 of sample s ----
    float* st = WST + (dir * 2048 + s) * 16 + kb;
    *(float4*)(st)     = make_float4(w2[0].x, w2[0].y, w2[1].x, w2[1].y);
    *(float4*)(st + 4) = make_float4(w2[2].x, w2[2].y, w2[3].x, w2[3].y);
}

// ---- epilogue: out[s,l] = sum_{m,n} L[m,s] T[m,n,l] R[n,s] (as r9) ----
__global__ __launch_bounds__(256)
void out_kernel(const float* __restrict__ T, const float* __restrict__ WST,
                float* __restrict__ OUT)
{
    __shared__ float sT[2560];
    const int tid = threadIdx.x;
    for (int k = tid; k < 640; k += 256)
        ((float4*)sT)[k] = ((const float4*)T)[k];
    __syncthreads();
    const int t = blockIdx.x * 256 + tid;      // < 20480
    const int s = t / 10, l = t - s * 10;
    const float* L = WST + s * 16;
    const float* R = WST + 2048 * 16 + s * 16;
    const float4 Ra = *(const float4*)(R);
    const float4 Rb = *(const float4*)(R + 4);
    const float4 Rc = *(const float4*)(R + 8);
    const float4 Rd = *(const float4*)(R + 12);
    float acc = 0.f;
#pragma unroll
    for (int m = 0; m < 16; ++m) {
        const float lm = L[m];
        const float* Tp = sT + m * 160 + l;
        acc = fmaf(lm * Ra.x, Tp[0],   acc);
        acc = fmaf(lm * Ra.y, Tp[10],  acc);
        acc = fmaf(lm * Ra.z, Tp[20],  acc);
        acc = fmaf(lm * Ra.w, Tp[30],  acc);
        acc = fmaf(lm * Rb.x, Tp[40],  acc);
        acc = fmaf(lm * Rb.y, Tp[50],  acc);
        acc = fmaf(lm * Rb.z, Tp[60],  acc);
        acc = fmaf(lm * Rb.w, Tp[70],  acc);
        acc = fmaf(lm * Rc.x, Tp[80],  acc);
        acc = fmaf(lm * Rc.y, Tp[90],  acc);
        acc = fmaf(lm * Rc.z, Tp[100], acc);
        acc = fmaf(lm * Rc.w, Tp[110], acc);
        acc = fmaf(lm * Rd.x, Tp[120], acc);
        acc = fmaf(lm * Rd.y, Tp[130], acc);
        acc = fmaf(lm * Rd.z, Tp[140], acc);
        acc = fmaf(lm * Rd.w, Tp[150], acc);
    }
    OUT[t] = acc;
}

extern "C" void kernel_launch(void* const* d_in, const int* in_sizes, int n_in,
                              void* d_out, int out_size, void* d_ws, size_t ws_size,
                              hipStream_t stream)
{
    const float* X  = (const float*)d_in[0];   // (2048,196,2)
    const float* AL = (const float*)d_in[1];   // (2,16)
    const float* AM = (const float*)d_in[2];   // (194,2,16,16)
    const float* AR = (const float*)d_in[3];   // (2,16)
    const float* T  = (const float*)d_in[4];   // (16,16,10)
    (void)in_sizes; (void)n_in; (void)out_size; (void)ws_size;
    unsigned* WS = (unsigned*)d_ws;            // pair G streams: 400 KB
    float* WST   = (float*)d_ws + STATE_DW;    // states: 256 KB
    float* OUT   = (float*)d_out;              // (2048,10)

    hipLaunchKernelGGL(prep_kernel,  dim3(100), dim3(256), 0, stream, AM, WS);
    hipLaunchKernelGGL(chain_kernel, dim3(128), dim3(64),  0, stream,
                       X, AL, AR, WS, WST);
    hipLaunchKernelGGL(out_kernel,   dim3(80),  dim3(256), 0, stream,
                       T, WST, OUT);
}

// Round 12
// 108.804 us; speedup vs baseline: 1.0258x; 1.0258x over previous
//
#include <hip/hip_runtime.h>

// QuantumDMRGLayer: B=2048, L=196, M=16, NBL=10, pos_label=98 (fixed by setup).
// Round-12: SEGMENTED chains. r7-r11 proved the pure-chain formulation caps at
// 128 waves (1% occupancy) -> ~600+ cyc/site of exposed latency no matter the
// inner loop. Fix: split each direction into 2 segments; far segments compute
// per-sample 16x16 segment-product matrices by evolving the 16 identity basis
// vectors through the SAME verified MFMA site-step (basis = 16x effective
// batch): 2048 extra waves -> 2176 total (~2.1/SIMD), latency finally hidden.
//   left  = (u0 . M_0..M_48) . (M_49..M_97)      = L1 . P_L
//   right = (M_98..M_145) . (M_146..M_193 . v0)  = P_R . R1
// Phase A (one kernel, 2176 x 1-wave blocks):
//   blocks 0..63    vector-left  (sites 0..48,  s = g*32+c)
//   blocks 64..127  vector-right (stream 0..47, sites 193..146)
//   blocks 128..1151 basis-left  (stream 49..97): cols = (sample, basis b),
//                    s = g*2+(c>>4), b = c&15, w init = identity row b
//   blocks 1152..2175 basis-right(stream 48..95): identity cols of P_R
//   basis results stored transposed-by-construction: PL[s][b][k] = P_L[b,k],
//   PR[s][j][k] = P_R[k,j].
// Phase B (out_kernel): fp32 fold left[k] = sum_b L1[b] PL[s][b][k],
//   right[k] = sum_j R1[j] PR[s][j][k], then out = left.T.right (as r9).
// Verified machinery unchanged (r7-r10, absmax 6.9e-18): pi = bit2<->bit3 row
// permutation in G so each lane's D regs are its own B k-half (zero cross-lane
// ops); split-bf16 Da=Gh*Vh || Db=Gh*Vl+Gl*Vh; 4-slot register prefetch ring;
// r9 prep kernel verbatim (same two G streams).

typedef __attribute__((ext_vector_type(8))) short short8;
typedef __attribute__((ext_vector_type(16))) float floatx16;
typedef __attribute__((ext_vector_type(2))) float float2v;

#define GSITE_DW 512                 // dwords per site (hi 256 | lo 256)
#define GDIR_DW (100 * GSITE_DW)     // 100 sites per dir (incl. pads)
#define L1OFF (2 * GDIR_DW)          // float offsets into d_ws
#define R1OFF (L1OFF + 2048 * 16)
#define PLOFF (R1OFF + 2048 * 16)
#define PROFF (PLOFF + 2048 * 256)

__device__ __forceinline__ unsigned bf16_rne(unsigned u) {
    return (u + 0x7FFFu + ((u >> 16) & 1u)) >> 16;
}

// ---- prep: build split-bf16, row-permuted G streams in d_ws (r9 verbatim) --
__global__ __launch_bounds__(256)
void prep_kernel(const float* __restrict__ AM, unsigned* __restrict__ WS)
{
    const int bid = blockIdx.x;                // 0..199
    const int dir = bid / 100;
    const int p   = bid % 100;
    const int lim = dir ? 96 : 98;
    const int a   = dir ? (193 - p) : p;
    const int t   = threadIdx.x;

    __shared__ float sM[512];                  // one site: [d][16][16]
    if (p < lim)
        ((float2*)sM)[t] = ((const float2*)(AM + a * 512))[t];
    else
        ((float2*)sM)[t] = make_float2(0.f, 0.f);   // pad sites -> zero
    __syncthreads();

    const int w    = t & 3;
    const int lane = t >> 2;
    const int kb = (lane >> 5) << 3;
    const int r  = lane & 31;
    const int rr = (r & 0x13) | ((r & 4) << 1) | ((r & 8) >> 1);  // pi(r)
    const int d = rr >> 4, nn = rr & 15;
    const int k0 = kb + 2 * w;

    float g0, g1;
    if (dir == 0) { g0 = sM[d * 256 + k0 * 16 + nn];
                    g1 = sM[d * 256 + (k0 + 1) * 16 + nn]; }
    else          { g0 = sM[d * 256 + nn * 16 + k0];
                    g1 = sM[d * 256 + nn * 16 + k0 + 1]; }

    const unsigned h0 = bf16_rne(__float_as_uint(g0));
    const unsigned h1 = bf16_rne(__float_as_uint(g1));
    const float l0f = g0 - __uint_as_float(h0 << 16);
    const float l1f = g1 - __uint_as_float(h1 << 16);
    const unsigned lo0 = bf16_rne(__float_as_uint(l0f));
    const unsigned lo1 = bf16_rne(__float_as_uint(l1f));

    unsigned* gp = WS + (dir * 100 + p) * GSITE_DW;
    gp[t]       = (h1 << 16) | h0;
    gp[256 + t] = (lo1 << 16) | lo0;
}

// ---- phase A: 2176 single-wave blocks, vector or basis segments ----
__global__ __launch_bounds__(64, 1)
void chain_kernel(const float* __restrict__ X,
                  const float* __restrict__ AL,
                  const float* __restrict__ AR,
                  const unsigned* __restrict__ WS,
                  float* __restrict__ WSF)
{
    const int lane = threadIdx.x;              // 0..63
    const int c    = lane & 31;                // column slot
    const int kb   = (lane >> 5) << 3;         // this lane's k-half base

    int bid = blockIdx.x, mode, dir, g;
    if (bid < 128) { mode = 0; dir = bid >> 6;  g = bid & 63; }
    else { bid -= 128; mode = 1; dir = bid >> 10; g = bid & 1023; }
    const int p0 = mode ? (dir ? 48 : 49) : 0; // stream start
    const int s  = mode ? (g * 2 + (c >> 4)) : (g * 32 + c);
    const int b  = c & 15;                     // basis index (mode 1)
    const float* Xs = X + s * 392;
    const unsigned* Gb = WS + dir * GDIR_DW + p0 * GSITE_DW + lane * 4;

    float2v w2[4];
    int4 vh4, vl4;
    auto packv = [&]() {                       // fp32 -> packed bf16 hi/lo
#pragma unroll
        for (int q = 0; q < 4; ++q) {
            const unsigned u0 = __float_as_uint(w2[q].x);
            const unsigned u1 = __float_as_uint(w2[q].y);
            float2v hi;
            hi.x = __uint_as_float(u0 & 0xFFFF0000u);
            hi.y = __uint_as_float(u1 & 0xFFFF0000u);
            const float2v lo = w2[q] - hi;
            ((unsigned*)&vh4)[q] = __builtin_amdgcn_perm(u1, u0, 0x07060302u);
            ((unsigned*)&vl4)[q] = __builtin_amdgcn_perm(
                __float_as_uint(lo.y), __float_as_uint(lo.x), 0x07060302u);
        }
    };

    // ---- init: boundary vector (mode 0) or identity basis row (mode 1) ----
    if (mode == 0) {
        const float* Ai = dir ? AR : AL;
        const float2 xi = *(const float2*)(Xs + (dir ? 390 : 0));
#pragma unroll
        for (int q = 0; q < 4; ++q) {
            w2[q].x = xi.x * Ai[kb + 2 * q]     + xi.y * Ai[16 + kb + 2 * q];
            w2[q].y = xi.x * Ai[kb + 2 * q + 1] + xi.y * Ai[16 + kb + 2 * q + 1];
        }
    } else {
#pragma unroll
        for (int q = 0; q < 4; ++q) {
            w2[q].x = (kb + 2 * q     == b) ? 1.f : 0.f;
            w2[q].y = (kb + 2 * q + 1 == b) ? 1.f : 0.f;
        }
    }
    packv();

    // x pair for ABSOLUTE stream position p: left site p -> col p+1;
    // right stream p = site 193-p -> col 194-p.
    auto xoff = [&](int p) { return dir ? (388 - 2 * p) : (2 * p + 2); };

    // ---- 4-slot register prefetch ring ----
    int4 GH[4], GL[4];
    float2 xr[4];
#pragma unroll
    for (int i = 0; i < 4; ++i) {
        GH[i] = *(const int4*)(Gb + i * GSITE_DW);
        GL[i] = *(const int4*)(Gb + i * GSITE_DW + 256);
        xr[i] = *(const float2*)(Xs + xoff(p0 + i));
    }

    auto site = [&](int j4, bool pf, int pr) {   // pr = RELATIVE prefetch pos
        const short8 ah = *(short8*)&GH[j4];
        const short8 al = *(short8*)&GL[j4];
        const short8 bh = *(short8*)&vh4;
        const short8 bl = *(short8*)&vl4;
        floatx16 Da = {}, Db = {};
        Da = __builtin_amdgcn_mfma_f32_32x32x16_bf16(ah, bh, Da, 0, 0, 0);
        Db = __builtin_amdgcn_mfma_f32_32x32x16_bf16(ah, bl, Db, 0, 0, 0);
        Db = __builtin_amdgcn_mfma_f32_32x32x16_bf16(al, bh, Db, 0, 0, 0);
        const float2 xs = xr[j4];
        if (pf) {
            GH[j4] = *(const int4*)(Gb + pr * GSITE_DW);
            GL[j4] = *(const int4*)(Gb + pr * GSITE_DW + 256);
            xr[j4] = *(const float2*)(Xs + xoff(p0 + pr));
        }
        const float2v xx = {xs.x, xs.x}, xy = {xs.y, xs.y};
#pragma unroll
        for (int q = 0; q < 4; ++q) {          // D[j]=W0, D[j+8]=W1, k=kb+j
            const float2v s0 = float2v{Da[2*q],   Da[2*q+1]} +
                               float2v{Db[2*q],   Db[2*q+1]};
            const float2v s1 = float2v{Da[2*q+8], Da[2*q+9]} +
                               float2v{Db[2*q+8], Db[2*q+9]};
            w2[q] = __builtin_elementwise_fma(xx, s0, xy * s1);
        }
        packv();
    };

    // ---- 12 chunks x 4 sites = 48 steps; left segments do one more ----
    for (int cc = 0; cc < 12; ++cc) {
#pragma unroll
        for (int j4 = 0; j4 < 4; ++j4)
            site(j4, true, 4 * cc + j4 + 4);   // prefetch stays in-bounds
    }
    if (dir == 0)                              // 49th step, slot 0 preloaded
        site(0, false, 0);

    // ---- store phase-A result ----
    float* dst;
    if (mode == 0) dst = WSF + (dir ? R1OFF : L1OFF) + s * 16 + kb;
    else           dst = WSF + (dir ? PROFF : PLOFF) + s * 256 + b * 16 + kb;
    *(float4*)(dst)     = make_float4(w2[0].x, w2[0].y, w2[1].x, w2[1].y);
    *(float4*)(dst + 4) = make_float4(w2[2].x, w2[2].y, w2[3].x, w2[3].y);
}

// ---- phase B: fold (fp32) + T contraction; block = 64 samples ----
__global__ __launch_bounds__(256)
void out_kernel(const float* __restrict__ T, const float* __restrict__ WSF,
                float* __restrict__ OUT)
{
    __shared__ float sT[2560];
    __shared__ float sL1[1024], sR1[1024];     // [64][16] boundary vectors
    __shared__ float sL[1024],  sR[1024];      // [64][16] folded vectors
    const int tid = threadIdx.x;
    const int s0  = (int)blockIdx.x * 64;

    for (int k = tid; k < 640; k += 256)
        ((float4*)sT)[k] = ((const float4*)T)[k];
    for (int k = tid; k < 1024; k += 256) {
        sL1[k] = WSF[L1OFF + s0 * 16 + k];
        sR1[k] = WSF[R1OFF + s0 * 16 + k];
    }
    __syncthreads();

    // fold: left[k] = sum_b L1[b] PL[s][b][k]; right[k] = sum_j R1[j] PR[s][j][k]
    for (int it = tid; it < 1024; it += 256) {
        const int sl = it >> 4, k = it & 15;
        const float* PLs = WSF + PLOFF + (size_t)(s0 + sl) * 256 + k;
        const float* PRs = WSF + PROFF + (size_t)(s0 + sl) * 256 + k;
        float accL = 0.f, accR = 0.f;
#pragma unroll
        for (int bb = 0; bb < 16; ++bb) {
            accL = fmaf(sL1[sl * 16 + bb], PLs[bb * 16], accL);
            accR = fmaf(sR1[sl * 16 + bb], PRs[bb * 16], accR);
        }
        sL[it] = accL;
        sR[it] = accR;
    }
    __syncthreads();

    // out[s,l] = sum_{m,n} left[m] T[m,n,l] right[n]
    for (int o = tid; o < 640; o += 256) {
        const int sl = o / 10, l = o - sl * 10;
        const float* L = sL + sl * 16;
        const float* R = sR + sl * 16;
        const float4 Ra = *(const float4*)(R);
        const float4 Rb = *(const float4*)(R + 4);
        const float4 Rc = *(const float4*)(R + 8);
        const float4 Rd = *(const float4*)(R + 12);
        float acc = 0.f;
#pragma unroll
        for (int m = 0; m < 16; ++m) {
            const float lm = L[m];
            const float* Tp = sT + m * 160 + l;
            acc = fmaf(lm * Ra.x, Tp[0],   acc);
            acc = fmaf(lm * Ra.y, Tp[10],  acc);
            acc = fmaf(lm * Ra.z, Tp[20],  acc);
            acc = fmaf(lm * Ra.w, Tp[30],  acc);
            acc = fmaf(lm * Rb.x, Tp[40],  acc);
            acc = fmaf(lm * Rb.y, Tp[50],  acc);
            acc = fmaf(lm * Rb.z, Tp[60],  acc);
            acc = fmaf(lm * Rb.w, Tp[70],  acc);
            acc = fmaf(lm * Rc.x, Tp[80],  acc);
            acc = fmaf(lm * Rc.y, Tp[90],  acc);
            acc = fmaf(lm * Rc.z, Tp[100], acc);
            acc = fmaf(lm * Rc.w, Tp[110], acc);
            acc = fmaf(lm * Rd.x, Tp[120], acc);
            acc = fmaf(lm * Rd.y, Tp[130], acc);
            acc = fmaf(lm * Rd.z, Tp[140], acc);
            acc = fmaf(lm * Rd.w, Tp[150], acc);
        }
        OUT[(s0 + sl) * 10 + l] = acc;
    }
}

extern "C" void kernel_launch(void* const* d_in, const int* in_sizes, int n_in,
                              void* d_out, int out_size, void* d_ws, size_t ws_size,
                              hipStream_t stream)
{
    const float* X  = (const float*)d_in[0];   // (2048,196,2)
    const float* AL = (const float*)d_in[1];   // (2,16)
    const float* AM = (const float*)d_in[2];   // (194,2,16,16)
    const float* AR = (const float*)d_in[3];   // (2,16)
    const float* T  = (const float*)d_in[4];   // (16,16,10)
    (void)in_sizes; (void)n_in; (void)out_size; (void)ws_size;
    unsigned* WS = (unsigned*)d_ws;            // G streams (400 KB)
    float* WSF   = (float*)d_ws;               // + states/products (~4.5 MB)
    float* OUT   = (float*)d_out;              // (2048,10)

    hipLaunchKernelGGL(prep_kernel,  dim3(200),  dim3(256), 0, stream, AM, WS);
    hipLaunchKernelGGL(chain_kernel, dim3(2176), dim3(64),  0, stream,
                       X, AL, AR, WS, WSF);
    hipLaunchKernelGGL(out_kernel,   dim3(32),   dim3(256), 0, stream,
                       T, WSF, OUT);
}